// Round 11
// baseline (308.092 us; speedup 1.0000x reference)
//
#include <hip/hip_runtime.h>
#include <hip/hip_cooperative_groups.h>
namespace cg = cooperative_groups;

#define N_NODES 100000
#define N_FEATS 256
#define OUT_DIM 64
#define NNZ_X   1280000
#define N_EDGES 1600000
#define NB      391     // ceil(N_NODES/256); bucket = row >> 8
#define CHUNK   2048    // entries per phase-1 block
#define KPT     8       // CHUNK/256 entries per thread
#define CAPX    4352    // X slab capacity (kept-mean 2949, sigma ~54: +25 sigma)
#define CAPA    5120    // A slab capacity (mean 4092, sigma ~64: +16 sigma)

// ---------------- JAX threefry2x32 (partitionable mode, verified R2) ----------------
__device__ __forceinline__ unsigned rotl32(unsigned x, unsigned d) {
    return (x << d) | (x >> (32u - d));
}

__device__ __forceinline__ float jax_uniform_42(unsigned e) {
    unsigned x0 = 0u, x1 = e;
    const unsigned ks0 = 0u, ks1 = 42u, ks2 = 0u ^ 42u ^ 0x1BD11BDAu;
    x0 += ks0; x1 += ks1;
#define TF_R(r) { x0 += x1; x1 = rotl32(x1, r); x1 ^= x0; }
    TF_R(13) TF_R(15) TF_R(26) TF_R(6)
    x0 += ks1; x1 += ks2 + 1u;
    TF_R(17) TF_R(29) TF_R(16) TF_R(24)
    x0 += ks2; x1 += ks0 + 2u;
    TF_R(13) TF_R(15) TF_R(26) TF_R(6)
    x0 += ks0; x1 += ks1 + 3u;
    TF_R(17) TF_R(29) TF_R(16) TF_R(24)
    x0 += ks1; x1 += ks2 + 4u;
    TF_R(13) TF_R(15) TF_R(26) TF_R(6)
    x0 += ks2; x1 += ks0 + 5u;
#undef TF_R
    unsigned bits = x0 ^ x1;
    return __uint_as_float((bits >> 9) | 0x3f800000u) - 1.0f;
}

__device__ __forceinline__ bool keep_42(unsigned e) {
    float u = jax_uniform_42(e);
    return floorf(0.9f + u) != 0.0f;
}

// ---------------- phase 1 (R9 verbatim): LDS-binned grouping into fixed slabs --
// Entry: float2(val, int(col<<8 | row&255)). Slab b = dst[b*CAP .. b*CAP+cnt_b).
__global__ void phase1(const float* __restrict__ fvals, const int* __restrict__ frows,
                       const int* __restrict__ fcols,
                       const float* __restrict__ avals, const int* __restrict__ arows,
                       const int* __restrict__ acols,
                       int* __restrict__ bcur_x, int* __restrict__ bcur_a,
                       float2* __restrict__ gx, float2* __restrict__ ga) {
    const int isA = blockIdx.y;
    const float* vals = isA ? avals : fvals;
    const int* rows   = isA ? arows : frows;
    const int* cols   = isA ? acols : fcols;
    int* bcur         = isA ? bcur_a : bcur_x;
    float2* dst       = isA ? ga : gx;
    const unsigned cap = isA ? CAPA : CAPX;
    const unsigned n  = isA ? N_EDGES : NNZ_X;

    unsigned t = threadIdx.x;
    unsigned base = blockIdx.x * CHUNK;
    if (base >= n) return;   // uniform per block (X side has fewer chunks)

    __shared__ int cnt[512];
    __shared__ int start[512];
    __shared__ int cur[512];
    __shared__ int gbase[NB];
    __shared__ int s[256];
    __shared__ unsigned pArr[CHUNK];   // (b<<19)|(rowlow<<11)|ilocal

    int rcache[KPT];                   // row if kept, else -1

    cnt[2*t] = 0; cnt[2*t+1] = 0;
    __syncthreads();
    #pragma unroll
    for (int k = 0; k < KPT; k++) {
        unsigned i = base + k * 256u + t;
        int r = -1;
        if (i < n) {
            int rr = rows[i];
            if (isA || keep_42(i)) r = rr;
        }
        rcache[k] = r;
        if (r >= 0) atomicAdd(&cnt[(unsigned)r >> 8], 1);
    }
    __syncthreads();
    s[t] = cnt[2*t] + cnt[2*t+1];
    __syncthreads();
    for (int off = 1; off < 256; off <<= 1) {
        int v = (t >= (unsigned)off) ? s[t - off] : 0;
        __syncthreads();
        s[t] += v;
        __syncthreads();
    }
    int excl = t ? s[t-1] : 0;
    int n_valid = s[255];
    start[2*t]   = excl;
    start[2*t+1] = excl + cnt[2*t];
    cur[2*t]     = excl;
    cur[2*t+1]   = excl + cnt[2*t];
    for (unsigned b = t; b < NB; b += 256u) {
        int cb = cnt[b];
        if (cb > 0) gbase[b] = atomicAdd(&bcur[b], cb);
    }
    __syncthreads();
    #pragma unroll
    for (int k = 0; k < KPT; k++) {
        int r = rcache[k];
        if (r >= 0) {
            unsigned b = (unsigned)r >> 8;
            int p = atomicAdd(&cur[b], 1);
            pArr[p] = (b << 19) | (((unsigned)r & 255u) << 11) | (k * 256u + t);
        }
    }
    __syncthreads();
    #pragma unroll
    for (int k = 0; k < KPT; k++) {
        int sidx = k * 256 + (int)t;
        if (sidx < n_valid) {
            unsigned m = pArr[sidx];
            unsigned b = m >> 19;
            unsigned rowlow = (m >> 11) & 255u;
            unsigned i = base + (m & 2047u);
            float v = vals[i];
            if (!isA) v *= (float)(1.0 / 0.9);
            unsigned packed = ((unsigned)cols[i] << 8) | rowlow;
            float2 e; e.x = v; e.y = __int_as_float((int)packed);
            dst[(size_t)b * cap + gbase[b] + (sidx - start[b])] = e;
        }
    }
}

// ---------------- fused: X-sort+SpMM1 | A-sort (stays in LDS) | grid.sync | SpMM2
// One block per 256-row bucket. 44KB LDS -> 3 blocks/CU; launch_bounds(512,4)
// caps VGPR at 128 -> >=2 blocks/CU co-resident -> 512 >= 391 grid fits.
__global__ __launch_bounds__(512, 4) void fused_sort_spmm(
        const int* __restrict__ bcur_x, const float2* __restrict__ gx,
        const float* __restrict__ W, unsigned short* __restrict__ xw,
        const int* __restrict__ bcur_a, const float2* __restrict__ ga,
        float* __restrict__ out) {
    __shared__ float2 ent[CAPA];       // 40 KB (CAPA >= CAPX)
    __shared__ int hist[256];
    __shared__ int starts[256];
    __shared__ int cursor[256];
    unsigned t = threadIdx.x;
    unsigned b = blockIdx.x;
    unsigned wid = t >> 6, lane = t & 63u;

    // ===== phase X: sort bucket's X entries into LDS, compute SpMM1 =====
    int cntx = bcur_x[b];
    {
        const float2* src = gx + (size_t)b * CAPX;
        if (t < 256) hist[t] = 0;
        __syncthreads();
        for (int i = (int)t; i < cntx; i += 512)
            atomicAdd(&hist[((unsigned)__float_as_int(src[i].y)) & 255u], 1);
        __syncthreads();
        if (t < 256) {
            for (int off = 1; off < 256; off <<= 1) {
                int v = (t >= (unsigned)off) ? hist[t - off] : 0;
                __syncthreads();
                hist[t] += v;
                __syncthreads();
            }
            int excl = t ? hist[t - 1] : 0;
            starts[t] = excl;
            cursor[t] = excl;
        } else {
            for (int off = 1; off < 256; off <<= 1) { __syncthreads(); __syncthreads(); }
        }
        __syncthreads();
        for (int i = (int)t; i < cntx; i += 512) {
            float2 e = src[i];
            int pos = atomicAdd(&cursor[((unsigned)__float_as_int(e.y)) & 255u], 1);
            ent[pos] = e;
        }
        __syncthreads();
        // SpMM1: 8 waves x 32 rows, unroll 8, W gathers (64KB, L1/L2-hot)
        for (unsigned r = wid; r < 256u; r += 8u) {
            int s0 = starts[r];
            int s1 = (r == 255u) ? cntx : starts[r + 1];
            float a[8];
            #pragma unroll
            for (int j = 0; j < 8; j++) a[j] = 0.0f;
            int p = s0;
            for (; p + 8 <= s1; p += 8) {
                float2 e[8];
                #pragma unroll
                for (int j = 0; j < 8; j++) e[j] = ent[p + j];
                float w[8];
                #pragma unroll
                for (int j = 0; j < 8; j++)
                    w[j] = W[(((unsigned)__float_as_int(e[j].y)) >> 8) * OUT_DIM + lane];
                #pragma unroll
                for (int j = 0; j < 8; j++) a[j] = fmaf(e[j].x, w[j], a[j]);
            }
            for (; p < s1; p++) {
                float2 e = ent[p];
                a[0] = fmaf(e.x, W[(((unsigned)__float_as_int(e.y)) >> 8) * OUT_DIM + lane], a[0]);
            }
            unsigned grow = (b << 8) + r;
            if (grow < N_NODES) {
                float acc = ((a[0] + a[1]) + (a[2] + a[3])) + ((a[4] + a[5]) + (a[6] + a[7]));
                unsigned bits = __float_as_uint(acc);
                unsigned rounded = (bits + 0x7fffu + ((bits >> 16) & 1u)) >> 16;
                xw[(size_t)grow * OUT_DIM + lane] = (unsigned short)rounded;
            }
        }
    }
    __syncthreads();   // all reads of ent/starts done before A overwrites them

    // ===== phase A: sort bucket's A entries into LDS (kept there) =====
    int cnta = bcur_a[b];
    {
        const float2* src = ga + (size_t)b * CAPA;
        if (t < 256) hist[t] = 0;
        __syncthreads();
        for (int i = (int)t; i < cnta; i += 512)
            atomicAdd(&hist[((unsigned)__float_as_int(src[i].y)) & 255u], 1);
        __syncthreads();
        if (t < 256) {
            for (int off = 1; off < 256; off <<= 1) {
                int v = (t >= (unsigned)off) ? hist[t - off] : 0;
                __syncthreads();
                hist[t] += v;
                __syncthreads();
            }
            int excl = t ? hist[t - 1] : 0;
            starts[t] = excl;
            cursor[t] = excl;
        } else {
            for (int off = 1; off < 256; off <<= 1) { __syncthreads(); __syncthreads(); }
        }
        __syncthreads();
        for (int i = (int)t; i < cnta; i += 512) {
            float2 e = src[i];
            int pos = atomicAdd(&cursor[((unsigned)__float_as_int(e.y)) & 255u], 1);
            ent[pos] = e;
        }
    }

    cg::this_grid().sync();   // xw fully written + device-visible; LDS ent/starts ready

    // ===== phase 2: SpMM2 + ReLU from LDS entries, bf16 xw gathers =====
    for (unsigned r = wid; r < 256u; r += 8u) {
        int s0 = starts[r];
        int s1 = (r == 255u) ? cnta : starts[r + 1];
        float a[8];
        #pragma unroll
        for (int j = 0; j < 8; j++) a[j] = 0.0f;
        int p = s0;
        for (; p + 16 <= s1; p += 16) {
            float2 e[16];
            #pragma unroll
            for (int j = 0; j < 16; j++) e[j] = ent[p + j];
            float x[16];
            #pragma unroll
            for (int j = 0; j < 16; j++)
                x[j] = __uint_as_float((unsigned)xw[(((unsigned)__float_as_int(e[j].y)) >> 8) * OUT_DIM + lane] << 16);
            #pragma unroll
            for (int j = 0; j < 16; j++)
                a[j & 7] = fmaf(e[j].x, x[j], a[j & 7]);
        }
        for (; p + 4 <= s1; p += 4) {
            float2 e[4];
            #pragma unroll
            for (int j = 0; j < 4; j++) e[j] = ent[p + j];
            #pragma unroll
            for (int j = 0; j < 4; j++) {
                float x = __uint_as_float((unsigned)xw[(((unsigned)__float_as_int(e[j].y)) >> 8) * OUT_DIM + lane] << 16);
                a[j] = fmaf(e[j].x, x, a[j]);
            }
        }
        for (; p < s1; p++) {
            float2 e = ent[p];
            float x = __uint_as_float((unsigned)xw[(((unsigned)__float_as_int(e.y)) >> 8) * OUT_DIM + lane] << 16);
            a[0] = fmaf(e.x, x, a[0]);
        }
        unsigned grow = (b << 8) + r;
        if (grow < N_NODES) {
            float acc = ((a[0] + a[1]) + (a[2] + a[3])) + ((a[4] + a[5]) + (a[6] + a[7]));
            out[(size_t)grow * OUT_DIM + lane] = fmaxf(acc, 0.0f);
        }
    }
}

extern "C" void kernel_launch(void* const* d_in, const int* in_sizes, int n_in,
                              void* d_out, int out_size, void* d_ws, size_t ws_size,
                              hipStream_t stream) {
    const float* feat_values = (const float*)d_in[0];
    const float* W           = (const float*)d_in[1];
    const float* adj_values  = (const float*)d_in[2];
    const int*   feat_rows   = (const int*)d_in[3];
    const int*   feat_cols   = (const int*)d_in[4];
    const int*   adj_rows    = (const int*)d_in[5];
    const int*   adj_cols    = (const int*)d_in[6];
    float* outp = (float*)d_out;

    // ---- workspace layout (bytes), total ~42.4 MB ----
    // bcur_x @ 0 (391 ints), bcur_a @ 2048
    // gx     @ 8192        : 391*CAPX*8 = 13,613,056
    // ga     @ 13,621,248  : 391*CAPA*8 = 16,015,360
    // xw     @ 29,636,608  : 100000*64*2 = 12,800,000
    char* ws = (char*)d_ws;
    int* bcur_x = (int*)(ws + 0);
    int* bcur_a = (int*)(ws + 2048);
    float2* gx  = (float2*)(ws + 8192);
    float2* ga  = (float2*)(ws + 13621248);
    unsigned short* xw = (unsigned short*)(ws + 29636608);

    hipMemsetAsync(ws, 0, 4096, stream);    // bucket cursors

    dim3 gp1((N_EDGES + CHUNK - 1) / CHUNK, 2);
    phase1<<<gp1, 256, 0, stream>>>(feat_values, feat_rows, feat_cols,
                                    adj_values, adj_rows, adj_cols,
                                    bcur_x, bcur_a, gx, ga);

    const float* Wc = W;
    void* kargs[] = { (void*)&bcur_x, (void*)&gx, (void*)&Wc, (void*)&xw,
                      (void*)&bcur_a, (void*)&ga, (void*)&outp };
    hipLaunchCooperativeKernel((void*)fused_sort_spmm, dim3(NB), dim3(512),
                               kargs, 0, stream);
}

// Round 12
// 223.116 us; speedup vs baseline: 1.3809x; 1.3809x over previous
//
#include <hip/hip_runtime.h>

#define N_NODES 100000
#define N_FEATS 256
#define OUT_DIM 64
#define NNZ_X   1280000
#define N_EDGES 1600000
#define NB      391     // ceil(N_NODES/256); bucket = row >> 8
#define CHUNK   4096    // entries per phase-1 block (512 thr, 8/thread)
#define KPT     8
#define CAPX    4352    // X slab capacity (kept-mean 2949, sigma ~54: +25 sigma)
#define CAPA    5120    // A slab capacity (mean 4092, sigma ~64: +16 sigma)

// ---------------- JAX threefry2x32 (partitionable mode, verified R2) ----------------
__device__ __forceinline__ unsigned rotl32(unsigned x, unsigned d) {
    return (x << d) | (x >> (32u - d));
}

__device__ __forceinline__ float jax_uniform_42(unsigned e) {
    unsigned x0 = 0u, x1 = e;
    const unsigned ks0 = 0u, ks1 = 42u, ks2 = 0u ^ 42u ^ 0x1BD11BDAu;
    x0 += ks0; x1 += ks1;
#define TF_R(r) { x0 += x1; x1 = rotl32(x1, r); x1 ^= x0; }
    TF_R(13) TF_R(15) TF_R(26) TF_R(6)
    x0 += ks1; x1 += ks2 + 1u;
    TF_R(17) TF_R(29) TF_R(16) TF_R(24)
    x0 += ks2; x1 += ks0 + 2u;
    TF_R(13) TF_R(15) TF_R(26) TF_R(6)
    x0 += ks0; x1 += ks1 + 3u;
    TF_R(17) TF_R(29) TF_R(16) TF_R(24)
    x0 += ks1; x1 += ks2 + 4u;
    TF_R(13) TF_R(15) TF_R(26) TF_R(6)
    x0 += ks2; x1 += ks0 + 5u;
#undef TF_R
    unsigned bits = x0 ^ x1;
    return __uint_as_float((bits >> 9) | 0x3f800000u) - 1.0f;
}

__device__ __forceinline__ bool keep_42(unsigned e) {
    float u = jax_uniform_42(e);
    return floorf(0.9f + u) != 0.0f;
}

// ---------------- phase 1: LDS-binned grouping into fixed slabs (512 thr) ------
// Entry: float2(val, int(col<<8 | row&255)). Slab b = dst[b*CAP .. b*CAP+cnt_b).
__global__ __launch_bounds__(512) void phase1(
        const float* __restrict__ fvals, const int* __restrict__ frows,
        const int* __restrict__ fcols,
        const float* __restrict__ avals, const int* __restrict__ arows,
        const int* __restrict__ acols,
        int* __restrict__ bcur_x, int* __restrict__ bcur_a,
        float2* __restrict__ gx, float2* __restrict__ ga) {
    const int isA = blockIdx.y;
    const float* vals = isA ? avals : fvals;
    const int* rows   = isA ? arows : frows;
    const int* cols   = isA ? acols : fcols;
    int* bcur         = isA ? bcur_a : bcur_x;
    float2* dst       = isA ? ga : gx;
    const unsigned cap = isA ? CAPA : CAPX;
    const unsigned n  = isA ? N_EDGES : NNZ_X;

    unsigned t = threadIdx.x;
    unsigned base = blockIdx.x * CHUNK;
    if (base >= n) return;   // uniform per block (X side has fewer chunks)

    __shared__ int cnt[512];
    __shared__ int start[512];
    __shared__ int cur[512];
    __shared__ int gbase[NB];
    __shared__ int s[256];
    __shared__ unsigned pArr[CHUNK];   // (b<<20)|(rowlow<<12)|ilocal

    int rcache[KPT];                   // row if kept, else -1

    cnt[t] = 0;
    __syncthreads();
    // pass 1: read rows once, hist kept entries per bucket
    #pragma unroll
    for (int k = 0; k < KPT; k++) {
        unsigned i = base + k * 512u + t;
        int r = -1;
        if (i < n) {
            int rr = rows[i];
            if (isA || keep_42(i)) r = rr;
        }
        rcache[k] = r;
        if (r >= 0) atomicAdd(&cnt[(unsigned)r >> 8], 1);
    }
    __syncthreads();
    // exclusive scan of 512 bins, threads 0..255 (2 bins each), uniform barriers
    if (t < 256) s[t] = cnt[2*t] + cnt[2*t+1];
    __syncthreads();
    for (int off = 1; off < 256; off <<= 1) {
        int v = (t < 256u && t >= (unsigned)off) ? s[t - off] : 0;
        __syncthreads();
        if (t < 256u) s[t] += v;
        __syncthreads();
    }
    if (t < 256u) {
        int excl = t ? s[t-1] : 0;
        start[2*t]   = excl;
        start[2*t+1] = excl + cnt[2*t];
        cur[2*t]     = excl;
        cur[2*t+1]   = excl + cnt[2*t];
    }
    for (unsigned b = t; b < NB; b += 512u) {
        int cb = cnt[b];
        if (cb > 0) gbase[b] = atomicAdd(&bcur[b], cb);
    }
    __syncthreads();
    int n_valid = s[255];
    // pass 2: bucket-grouped permutation from register cache
    #pragma unroll
    for (int k = 0; k < KPT; k++) {
        int r = rcache[k];
        if (r >= 0) {
            unsigned b = (unsigned)r >> 8;
            int p = atomicAdd(&cur[b], 1);
            pArr[p] = (b << 20) | (((unsigned)r & 255u) << 12) | (k * 512u + t);
        }
    }
    __syncthreads();
    // pass 3: coalesced slab writes; gather cols/vals from the 16KB window
    #pragma unroll
    for (int k = 0; k < KPT; k++) {
        int sidx = k * 512 + (int)t;
        if (sidx < n_valid) {
            unsigned m = pArr[sidx];
            unsigned b = m >> 20;
            unsigned rowlow = (m >> 12) & 255u;
            unsigned i = base + (m & 4095u);
            float v = vals[i];
            if (!isA) v *= (float)(1.0 / 0.9);
            unsigned packed = ((unsigned)cols[i] << 8) | rowlow;
            float2 e; e.x = v; e.y = __int_as_float((int)packed);
            dst[(size_t)b * cap + gbase[b] + (sidx - start[b])] = e;
        }
    }
}

// ---------------- fused sort stage (R9 verbatim): grid 2*NB --------------------
// blocks [0, NB)      : X bucket -> LDS row-sort -> SpMM1 -> bf16 xw
// blocks [NB, 2*NB)   : A bucket -> LDS row-sort -> write back slab + rs_a
__global__ __launch_bounds__(512) void sort_stage(
        const int* __restrict__ bcur_x, const float2* __restrict__ gx,
        const float* __restrict__ W, unsigned short* __restrict__ xw,
        const int* __restrict__ bcur_a, float2* __restrict__ ga,
        unsigned short* __restrict__ rs) {
    __shared__ float2 ent[CAPA];       // 41 KB (CAPA >= CAPX)
    __shared__ int hist[256];
    __shared__ int starts[256];
    __shared__ int cursor[256];
    unsigned t = threadIdx.x;
    const int isA = (blockIdx.x >= NB);
    unsigned b = isA ? (blockIdx.x - NB) : blockIdx.x;

    if (!isA) {
        int cnt = bcur_x[b];
        const float2* src = gx + (size_t)b * CAPX;
        if (t < 256) hist[t] = 0;
        __syncthreads();
        for (int i = (int)t; i < cnt; i += 512)
            atomicAdd(&hist[((unsigned)__float_as_int(src[i].y)) & 255u], 1);
        __syncthreads();
        if (t < 256) {
            for (int off = 1; off < 256; off <<= 1) {
                int v = (t >= (unsigned)off) ? hist[t - off] : 0;
                __syncthreads();
                hist[t] += v;
                __syncthreads();
            }
            int excl = t ? hist[t - 1] : 0;
            starts[t] = excl;
            cursor[t] = excl;
        } else {
            for (int off = 1; off < 256; off <<= 1) { __syncthreads(); __syncthreads(); }
        }
        __syncthreads();
        for (int i = (int)t; i < cnt; i += 512) {
            float2 e = src[i];
            int pos = atomicAdd(&cursor[((unsigned)__float_as_int(e.y)) & 255u], 1);
            ent[pos] = e;
        }
        __syncthreads();
        unsigned wid = t >> 6, lane = t & 63u;
        for (unsigned r = wid; r < 256u; r += 8u) {
            int s0 = starts[r];
            int s1 = (r == 255u) ? cnt : starts[r + 1];
            float a[8];
            #pragma unroll
            for (int j = 0; j < 8; j++) a[j] = 0.0f;
            int p = s0;
            for (; p + 8 <= s1; p += 8) {
                float2 e[8];
                #pragma unroll
                for (int j = 0; j < 8; j++) e[j] = ent[p + j];
                float w[8];
                #pragma unroll
                for (int j = 0; j < 8; j++)
                    w[j] = W[(((unsigned)__float_as_int(e[j].y)) >> 8) * OUT_DIM + lane];
                #pragma unroll
                for (int j = 0; j < 8; j++) a[j] = fmaf(e[j].x, w[j], a[j]);
            }
            for (; p < s1; p++) {
                float2 e = ent[p];
                a[0] = fmaf(e.x, W[(((unsigned)__float_as_int(e.y)) >> 8) * OUT_DIM + lane], a[0]);
            }
            unsigned grow = (b << 8) + r;
            if (grow < N_NODES) {
                float acc = ((a[0] + a[1]) + (a[2] + a[3])) + ((a[4] + a[5]) + (a[6] + a[7]));
                unsigned bits = __float_as_uint(acc);
                unsigned rounded = (bits + 0x7fffu + ((bits >> 16) & 1u)) >> 16;
                xw[(size_t)grow * OUT_DIM + lane] = (unsigned short)rounded;
            }
        }
    } else {
        int cnt = bcur_a[b];
        float2* g = ga + (size_t)b * CAPA;
        if (t < 256) hist[t] = 0;
        __syncthreads();
        for (int i = (int)t; i < cnt; i += 512) {
            float2 e = g[i];
            ent[i] = e;
            atomicAdd(&hist[((unsigned)__float_as_int(e.y)) & 255u], 1);
        }
        __syncthreads();
        if (t < 256) {
            for (int off = 1; off < 256; off <<= 1) {
                int v = (t >= (unsigned)off) ? hist[t - off] : 0;
                __syncthreads();
                hist[t] += v;
                __syncthreads();
            }
            int excl = t ? hist[t - 1] : 0;
            cursor[t] = excl;
            rs[(b << 8) + t] = (unsigned short)excl;
        } else {
            for (int off = 1; off < 256; off <<= 1) { __syncthreads(); __syncthreads(); }
        }
        __syncthreads();
        for (int i = (int)t; i < cnt; i += 512) {
            float2 e = ent[i];
            unsigned packed = (unsigned)__float_as_int(e.y);
            int pos = atomicAdd(&cursor[packed & 255u], 1);
            float2 o; o.x = e.x; o.y = __int_as_float((int)(packed >> 8));
            g[pos] = o;
        }
    }
}

// ---------------- SpMM2 + ReLU: half-wave ushort2 gather -----------------------
// lane = (half, dim-pair): 32 lanes cover a row via ushort2 (2 bf16 dims).
// Per 8-entry batch each half gathers 4 -> VMEM instr count halved vs R9.
__global__ void spmm2(const int* __restrict__ bcur_a,
                      const unsigned short* __restrict__ rs_a,
                      const float2* __restrict__ ga,
                      const unsigned short* __restrict__ xw,
                      float* __restrict__ out) {
    unsigned row  = blockIdx.x * 4u + (threadIdx.x >> 6);
    unsigned lane = threadIdx.x & 63u;
    if (row >= N_NODES) return;
    unsigned b = row >> 8, rl = row & 255u;
    int cnt = bcur_a[b];
    const float2* ent = ga + (size_t)b * CAPA;
    int s0 = rs_a[row];
    int s1 = (rl == 255u) ? cnt : (int)rs_a[row + 1];
    unsigned half = lane >> 5;          // which entry sub-batch
    unsigned sub  = lane & 31u;         // dim pair: dims (2*sub, 2*sub+1)
    const ushort2* xw2 = (const ushort2*)xw;   // row stride = 32 ushort2

    float2 acc[4];
    #pragma unroll
    for (int j = 0; j < 4; j++) { acc[j].x = 0.0f; acc[j].y = 0.0f; }
    int p = s0;
    for (; p + 8 <= s1; p += 8) {
        float2 e[4];
        #pragma unroll
        for (int j = 0; j < 4; j++) e[j] = ent[p + 4 * half + j];
        ushort2 u[4];
        #pragma unroll
        for (int j = 0; j < 4; j++)
            u[j] = xw2[((unsigned)__float_as_int(e[j].y)) * 32u + sub];
        #pragma unroll
        for (int j = 0; j < 4; j++) {
            float xx = __uint_as_float((unsigned)u[j].x << 16);
            float xy = __uint_as_float((unsigned)u[j].y << 16);
            acc[j].x = fmaf(e[j].x, xx, acc[j].x);
            acc[j].y = fmaf(e[j].x, xy, acc[j].y);
        }
    }
    // remainder: half h takes entries with parity h
    for (int q = p + (int)half; q < s1; q += 2) {
        float2 e = ent[q];
        ushort2 u = xw2[((unsigned)__float_as_int(e.y)) * 32u + sub];
        acc[0].x = fmaf(e.x, __uint_as_float((unsigned)u.x << 16), acc[0].x);
        acc[0].y = fmaf(e.x, __uint_as_float((unsigned)u.y << 16), acc[0].y);
    }
    float ax = (acc[0].x + acc[1].x) + (acc[2].x + acc[3].x);
    float ay = (acc[0].y + acc[1].y) + (acc[2].y + acc[3].y);
    // combine the two halves (partner lane = lane ^ 32)
    ax += __shfl(ax, (int)(lane ^ 32u), 64);
    ay += __shfl(ay, (int)(lane ^ 32u), 64);
    if (half == 0) {
        float2 o;
        o.x = fmaxf(ax, 0.0f);
        o.y = fmaxf(ay, 0.0f);
        ((float2*)out)[(size_t)row * 32u + sub] = o;
    }
}

extern "C" void kernel_launch(void* const* d_in, const int* in_sizes, int n_in,
                              void* d_out, int out_size, void* d_ws, size_t ws_size,
                              hipStream_t stream) {
    const float* feat_values = (const float*)d_in[0];
    const float* W           = (const float*)d_in[1];
    const float* adj_values  = (const float*)d_in[2];
    const int*   feat_rows   = (const int*)d_in[3];
    const int*   feat_cols   = (const int*)d_in[4];
    const int*   adj_rows    = (const int*)d_in[5];
    const int*   adj_cols    = (const int*)d_in[6];
    float* out = (float*)d_out;

    // ---- workspace layout (bytes) ----
    // bcur_x @ 0 (391 ints), bcur_a @ 2048
    // rs_a   @ 4096        : 100096 ushort = 200,192
    // gx     @ 204800      : 391*CAPX*8 = 13,613,056
    // ga     @ 13,817,856  : 391*CAPA*8 = 16,015,360
    // xw     @ 29,833,216  : 100000*64*2 = 12,800,000   (total ~42.6 MB)
    char* ws = (char*)d_ws;
    int* bcur_x = (int*)(ws + 0);
    int* bcur_a = (int*)(ws + 2048);
    unsigned short* rs_a = (unsigned short*)(ws + 4096);
    float2* gx  = (float2*)(ws + 204800);
    float2* ga  = (float2*)(ws + 13817856);
    unsigned short* xw = (unsigned short*)(ws + 29833216);

    hipMemsetAsync(ws, 0, 4096, stream);    // bucket cursors

    // phase1: grid sized for the larger (A) side; X blocks past 313 early-exit
    dim3 gp1((N_EDGES + CHUNK - 1) / CHUNK, 2);
    phase1<<<gp1, 512, 0, stream>>>(feat_values, feat_rows, feat_cols,
                                    adj_values, adj_rows, adj_cols,
                                    bcur_x, bcur_a, gx, ga);
    sort_stage<<<2 * NB, 512, 0, stream>>>(bcur_x, gx, W, xw, bcur_a, ga, rs_a);
    spmm2<<<(N_NODES + 3) / 4, 256, 0, stream>>>(bcur_a, rs_a, ga, xw, out);
}

// Round 13
// 215.516 us; speedup vs baseline: 1.4296x; 1.0353x over previous
//
#include <hip/hip_runtime.h>

#define N_NODES 100000
#define N_FEATS 256
#define OUT_DIM 64
#define NNZ_X   1280000
#define N_EDGES 1600000
#define NB      391     // ceil(N_NODES/256); bucket = row >> 8
#define CHUNK   4096    // entries per phase-1 block (512 thr, 8/thread)
#define KPT     8
#define CAPX    4352    // X slab capacity (kept-mean 2949, sigma ~54: +25 sigma)
#define CAPA    5120    // A slab capacity (mean 4092, sigma ~64: +16 sigma)

// ---------------- JAX threefry2x32 (partitionable mode, verified R2) ----------------
__device__ __forceinline__ unsigned rotl32(unsigned x, unsigned d) {
    return (x << d) | (x >> (32u - d));
}

__device__ __forceinline__ float jax_uniform_42(unsigned e) {
    unsigned x0 = 0u, x1 = e;
    const unsigned ks0 = 0u, ks1 = 42u, ks2 = 0u ^ 42u ^ 0x1BD11BDAu;
    x0 += ks0; x1 += ks1;
#define TF_R(r) { x0 += x1; x1 = rotl32(x1, r); x1 ^= x0; }
    TF_R(13) TF_R(15) TF_R(26) TF_R(6)
    x0 += ks1; x1 += ks2 + 1u;
    TF_R(17) TF_R(29) TF_R(16) TF_R(24)
    x0 += ks2; x1 += ks0 + 2u;
    TF_R(13) TF_R(15) TF_R(26) TF_R(6)
    x0 += ks0; x1 += ks1 + 3u;
    TF_R(17) TF_R(29) TF_R(16) TF_R(24)
    x0 += ks1; x1 += ks2 + 4u;
    TF_R(13) TF_R(15) TF_R(26) TF_R(6)
    x0 += ks2; x1 += ks0 + 5u;
#undef TF_R
    unsigned bits = x0 ^ x1;
    return __uint_as_float((bits >> 9) | 0x3f800000u) - 1.0f;
}

__device__ __forceinline__ bool keep_42(unsigned e) {
    float u = jax_uniform_42(e);
    return floorf(0.9f + u) != 0.0f;
}

// f32 -> bf16 round-to-nearest-even
__device__ __forceinline__ unsigned short f32_bf16(float f) {
    unsigned bits = __float_as_uint(f);
    return (unsigned short)((bits + 0x7fffu + ((bits >> 16) & 1u)) >> 16);
}

// ---------------- phase 1 (R12 verbatim): LDS-binned grouping, 512 thr ---------
__global__ __launch_bounds__(512) void phase1(
        const float* __restrict__ fvals, const int* __restrict__ frows,
        const int* __restrict__ fcols,
        const float* __restrict__ avals, const int* __restrict__ arows,
        const int* __restrict__ acols,
        int* __restrict__ bcur_x, int* __restrict__ bcur_a,
        float2* __restrict__ gx, float2* __restrict__ ga) {
    const int isA = blockIdx.y;
    const float* vals = isA ? avals : fvals;
    const int* rows   = isA ? arows : frows;
    const int* cols   = isA ? acols : fcols;
    int* bcur         = isA ? bcur_a : bcur_x;
    float2* dst       = isA ? ga : gx;
    const unsigned cap = isA ? CAPA : CAPX;
    const unsigned n  = isA ? N_EDGES : NNZ_X;

    unsigned t = threadIdx.x;
    unsigned base = blockIdx.x * CHUNK;
    if (base >= n) return;

    __shared__ int cnt[512];
    __shared__ int start[512];
    __shared__ int cur[512];
    __shared__ int gbase[NB];
    __shared__ int s[256];
    __shared__ unsigned pArr[CHUNK];   // (b<<20)|(rowlow<<12)|ilocal

    int rcache[KPT];

    cnt[t] = 0;
    __syncthreads();
    #pragma unroll
    for (int k = 0; k < KPT; k++) {
        unsigned i = base + k * 512u + t;
        int r = -1;
        if (i < n) {
            int rr = rows[i];
            if (isA || keep_42(i)) r = rr;
        }
        rcache[k] = r;
        if (r >= 0) atomicAdd(&cnt[(unsigned)r >> 8], 1);
    }
    __syncthreads();
    if (t < 256) s[t] = cnt[2*t] + cnt[2*t+1];
    __syncthreads();
    for (int off = 1; off < 256; off <<= 1) {
        int v = (t < 256u && t >= (unsigned)off) ? s[t - off] : 0;
        __syncthreads();
        if (t < 256u) s[t] += v;
        __syncthreads();
    }
    if (t < 256u) {
        int excl = t ? s[t-1] : 0;
        start[2*t]   = excl;
        start[2*t+1] = excl + cnt[2*t];
        cur[2*t]     = excl;
        cur[2*t+1]   = excl + cnt[2*t];
    }
    for (unsigned b = t; b < NB; b += 512u) {
        int cb = cnt[b];
        if (cb > 0) gbase[b] = atomicAdd(&bcur[b], cb);
    }
    __syncthreads();
    int n_valid = s[255];
    #pragma unroll
    for (int k = 0; k < KPT; k++) {
        int r = rcache[k];
        if (r >= 0) {
            unsigned b = (unsigned)r >> 8;
            int p = atomicAdd(&cur[b], 1);
            pArr[p] = (b << 20) | (((unsigned)r & 255u) << 12) | (k * 512u + t);
        }
    }
    __syncthreads();
    #pragma unroll
    for (int k = 0; k < KPT; k++) {
        int sidx = k * 512 + (int)t;
        if (sidx < n_valid) {
            unsigned m = pArr[sidx];
            unsigned b = m >> 20;
            unsigned rowlow = (m >> 12) & 255u;
            unsigned i = base + (m & 4095u);
            float v = vals[i];
            if (!isA) v *= (float)(1.0 / 0.9);
            unsigned packed = ((unsigned)cols[i] << 8) | rowlow;
            float2 e; e.x = v; e.y = __int_as_float((int)packed);
            dst[(size_t)b * cap + gbase[b] + (sidx - start[b])] = e;
        }
    }
}

// ---------------- sort stage: grid 2*NB, LDS = CAPX only ----------------------
// blocks [0, NB):    X bucket -> LDS row-sort -> SpMM1 (half-wave W) -> bf16 xw
// blocks [NB, 2*NB): A bucket -> register-staged in-place sort + rs_a
// Shuffle-based 256-bin scan: waves 0-3 scan 64 bins each, 2 barriers.
__global__ __launch_bounds__(512) void sort_stage(
        const int* __restrict__ bcur_x, const float2* __restrict__ gx,
        const float* __restrict__ W, unsigned short* __restrict__ xw,
        const int* __restrict__ bcur_a, float2* __restrict__ ga,
        unsigned short* __restrict__ rs) {
    __shared__ float2 ent[CAPX];       // 34.8 KB
    __shared__ int hist[256];
    __shared__ int starts[256];
    __shared__ int cursor[256];
    __shared__ int wtot[4];
    unsigned t = threadIdx.x;
    unsigned wid = t >> 6, lane = t & 63u;
    const int isA = (blockIdx.x >= NB);
    unsigned b = isA ? (blockIdx.x - NB) : blockIdx.x;

    if (!isA) {
        // ================= X path =================
        int cnt = bcur_x[b];
        const float2* src = gx + (size_t)b * CAPX;
        if (t < 256) hist[t] = 0;
        __syncthreads();
        for (int i = (int)t; i < cnt; i += 512)
            atomicAdd(&hist[((unsigned)__float_as_int(src[i].y)) & 255u], 1);
        __syncthreads();
        // shuffle scan of 256 bins (waves 0-3)
        int inc = 0, binv = 0;
        if (wid < 4u) {
            unsigned bin = wid * 64u + lane;
            binv = hist[bin];
            inc = binv;
            #pragma unroll
            for (int d = 1; d < 64; d <<= 1) {
                int v = __shfl_up(inc, d, 64);
                if (lane >= (unsigned)d) inc += v;
            }
            if (lane == 63u) wtot[wid] = inc;
        }
        __syncthreads();
        if (wid < 4u) {
            int offw = 0;
            #pragma unroll
            for (int w = 0; w < 4; w++) if ((unsigned)w < wid) offw += wtot[w];
            unsigned bin = wid * 64u + lane;
            int excl = inc - binv + offw;
            starts[bin] = excl;
            cursor[bin] = excl;
        }
        __syncthreads();
        for (int i = (int)t; i < cnt; i += 512) {
            float2 e = src[i];
            int pos = atomicAdd(&cursor[((unsigned)__float_as_int(e.y)) & 255u], 1);
            ent[pos] = e;
        }
        __syncthreads();
        // SpMM1: 8 waves x 32 rows; half-wave float2 W gathers
        unsigned half = lane >> 5, sub = lane & 31u;
        const float2* W2 = (const float2*)W;       // row stride 32 float2
        ushort2* xw2 = (ushort2*)xw;               // row stride 32 ushort2
        for (unsigned r = wid; r < 256u; r += 8u) {
            int s0 = starts[r];
            int s1 = (r == 255u) ? cnt : starts[r + 1];
            float2 acc[4];
            #pragma unroll
            for (int j = 0; j < 4; j++) { acc[j].x = 0.0f; acc[j].y = 0.0f; }
            int p = s0;
            for (; p + 8 <= s1; p += 8) {
                float2 e[4];
                #pragma unroll
                for (int j = 0; j < 4; j++) e[j] = ent[p + 4 * half + j];
                float2 w[4];
                #pragma unroll
                for (int j = 0; j < 4; j++)
                    w[j] = W2[(((unsigned)__float_as_int(e[j].y)) >> 8) * 32u + sub];
                #pragma unroll
                for (int j = 0; j < 4; j++) {
                    acc[j].x = fmaf(e[j].x, w[j].x, acc[j].x);
                    acc[j].y = fmaf(e[j].x, w[j].y, acc[j].y);
                }
            }
            for (int q = p + (int)half; q < s1; q += 2) {
                float2 e = ent[q];
                float2 w = W2[(((unsigned)__float_as_int(e.y)) >> 8) * 32u + sub];
                acc[0].x = fmaf(e.x, w.x, acc[0].x);
                acc[0].y = fmaf(e.x, w.y, acc[0].y);
            }
            float ax = (acc[0].x + acc[1].x) + (acc[2].x + acc[3].x);
            float ay = (acc[0].y + acc[1].y) + (acc[2].y + acc[3].y);
            ax += __shfl(ax, (int)(lane ^ 32u), 64);
            ay += __shfl(ay, (int)(lane ^ 32u), 64);
            unsigned grow = (b << 8) + r;
            if (half == 0 && grow < N_NODES) {
                ushort2 o; o.x = f32_bf16(ax); o.y = f32_bf16(ay);
                xw2[(size_t)grow * 32u + sub] = o;
            }
        }
    } else {
        // ================= A path: register-staged in-place sort =================
        int cnt = bcur_a[b];
        float2* g = ga + (size_t)b * CAPA;
        if (t < 256) hist[t] = 0;
        __syncthreads();
        float2 ec[10];
        #pragma unroll
        for (int k = 0; k < 10; k++) {
            int i = k * 512 + (int)t;
            if (i < cnt) {
                float2 e = g[i];
                ec[k] = e;
                atomicAdd(&hist[((unsigned)__float_as_int(e.y)) & 255u], 1);
            }
        }
        __syncthreads();
        int inc = 0, binv = 0;
        if (wid < 4u) {
            unsigned bin = wid * 64u + lane;
            binv = hist[bin];
            inc = binv;
            #pragma unroll
            for (int d = 1; d < 64; d <<= 1) {
                int v = __shfl_up(inc, d, 64);
                if (lane >= (unsigned)d) inc += v;
            }
            if (lane == 63u) wtot[wid] = inc;
        }
        __syncthreads();
        if (wid < 4u) {
            int offw = 0;
            #pragma unroll
            for (int w = 0; w < 4; w++) if ((unsigned)w < wid) offw += wtot[w];
            unsigned bin = wid * 64u + lane;
            int excl = inc - binv + offw;
            cursor[bin] = excl;
            rs[(b << 8) + bin] = (unsigned short)excl;
        }
        __syncthreads();
        // all reads done (pre-barrier); claim positions and write back sorted
        #pragma unroll
        for (int k = 0; k < 10; k++) {
            int i = k * 512 + (int)t;
            if (i < cnt) {
                unsigned packed = (unsigned)__float_as_int(ec[k].y);
                int pos = atomicAdd(&cursor[packed & 255u], 1);
                float2 o; o.x = ec[k].x; o.y = __int_as_float((int)(packed >> 8));
                g[pos] = o;
            }
        }
    }
}

// ---------------- SpMM2 + ReLU (R12 verbatim): half-wave ushort2 gather --------
__global__ void spmm2(const int* __restrict__ bcur_a,
                      const unsigned short* __restrict__ rs_a,
                      const float2* __restrict__ ga,
                      const unsigned short* __restrict__ xw,
                      float* __restrict__ out) {
    unsigned row  = blockIdx.x * 4u + (threadIdx.x >> 6);
    unsigned lane = threadIdx.x & 63u;
    if (row >= N_NODES) return;
    unsigned b = row >> 8, rl = row & 255u;
    int cnt = bcur_a[b];
    const float2* ent = ga + (size_t)b * CAPA;
    int s0 = rs_a[row];
    int s1 = (rl == 255u) ? cnt : (int)rs_a[row + 1];
    unsigned half = lane >> 5;
    unsigned sub  = lane & 31u;
    const ushort2* xw2 = (const ushort2*)xw;

    float2 acc[4];
    #pragma unroll
    for (int j = 0; j < 4; j++) { acc[j].x = 0.0f; acc[j].y = 0.0f; }
    int p = s0;
    for (; p + 8 <= s1; p += 8) {
        float2 e[4];
        #pragma unroll
        for (int j = 0; j < 4; j++) e[j] = ent[p + 4 * half + j];
        ushort2 u[4];
        #pragma unroll
        for (int j = 0; j < 4; j++)
            u[j] = xw2[((unsigned)__float_as_int(e[j].y)) * 32u + sub];
        #pragma unroll
        for (int j = 0; j < 4; j++) {
            float xx = __uint_as_float((unsigned)u[j].x << 16);
            float xy = __uint_as_float((unsigned)u[j].y << 16);
            acc[j].x = fmaf(e[j].x, xx, acc[j].x);
            acc[j].y = fmaf(e[j].x, xy, acc[j].y);
        }
    }
    for (int q = p + (int)half; q < s1; q += 2) {
        float2 e = ent[q];
        ushort2 u = xw2[((unsigned)__float_as_int(e.y)) * 32u + sub];
        acc[0].x = fmaf(e.x, __uint_as_float((unsigned)u.x << 16), acc[0].x);
        acc[0].y = fmaf(e.x, __uint_as_float((unsigned)u.y << 16), acc[0].y);
    }
    float ax = (acc[0].x + acc[1].x) + (acc[2].x + acc[3].x);
    float ay = (acc[0].y + acc[1].y) + (acc[2].y + acc[3].y);
    ax += __shfl(ax, (int)(lane ^ 32u), 64);
    ay += __shfl(ay, (int)(lane ^ 32u), 64);
    if (half == 0) {
        float2 o;
        o.x = fmaxf(ax, 0.0f);
        o.y = fmaxf(ay, 0.0f);
        ((float2*)out)[(size_t)row * 32u + sub] = o;
    }
}

extern "C" void kernel_launch(void* const* d_in, const int* in_sizes, int n_in,
                              void* d_out, int out_size, void* d_ws, size_t ws_size,
                              hipStream_t stream) {
    const float* feat_values = (const float*)d_in[0];
    const float* W           = (const float*)d_in[1];
    const float* adj_values  = (const float*)d_in[2];
    const int*   feat_rows   = (const int*)d_in[3];
    const int*   feat_cols   = (const int*)d_in[4];
    const int*   adj_rows    = (const int*)d_in[5];
    const int*   adj_cols    = (const int*)d_in[6];
    float* out = (float*)d_out;

    // ---- workspace layout (bytes) ----
    char* ws = (char*)d_ws;
    int* bcur_x = (int*)(ws + 0);
    int* bcur_a = (int*)(ws + 2048);
    unsigned short* rs_a = (unsigned short*)(ws + 4096);
    float2* gx  = (float2*)(ws + 204800);
    float2* ga  = (float2*)(ws + 13817856);
    unsigned short* xw = (unsigned short*)(ws + 29833216);

    hipMemsetAsync(ws, 0, 4096, stream);    // bucket cursors

    dim3 gp1((N_EDGES + CHUNK - 1) / CHUNK, 2);
    phase1<<<gp1, 512, 0, stream>>>(feat_values, feat_rows, feat_cols,
                                    adj_values, adj_rows, adj_cols,
                                    bcur_x, bcur_a, gx, ga);
    sort_stage<<<2 * NB, 512, 0, stream>>>(bcur_x, gx, W, xw, bcur_a, ga, rs_a);
    spmm2<<<(N_NODES + 3) / 4, 256, 0, stream>>>(bcur_a, rs_a, ga, xw, out);
}

// Round 14
// 209.658 us; speedup vs baseline: 1.4695x; 1.0279x over previous
//
#include <hip/hip_runtime.h>

#define N_NODES 100000
#define N_FEATS 256
#define OUT_DIM 64
#define NNZ_X   1280000
#define N_EDGES 1600000
#define NB      391     // ceil(N_NODES/256); bucket = row >> 8
#define CHUNK   4096    // entries per phase-1 block (512 thr, 8/thread)
#define KPT     8
#define CAPX    4352    // X slab capacity (kept-mean 2949, sigma ~54: +25 sigma)
#define CAPA    5120    // A slab capacity (mean 4092, sigma ~64: +16 sigma)

// ---------------- JAX threefry2x32 (partitionable mode, verified R2) ----------------
__device__ __forceinline__ unsigned rotl32(unsigned x, unsigned d) {
    return (x << d) | (x >> (32u - d));
}

__device__ __forceinline__ float jax_uniform_42(unsigned e) {
    unsigned x0 = 0u, x1 = e;
    const unsigned ks0 = 0u, ks1 = 42u, ks2 = 0u ^ 42u ^ 0x1BD11BDAu;
    x0 += ks0; x1 += ks1;
#define TF_R(r) { x0 += x1; x1 = rotl32(x1, r); x1 ^= x0; }
    TF_R(13) TF_R(15) TF_R(26) TF_R(6)
    x0 += ks1; x1 += ks2 + 1u;
    TF_R(17) TF_R(29) TF_R(16) TF_R(24)
    x0 += ks2; x1 += ks0 + 2u;
    TF_R(13) TF_R(15) TF_R(26) TF_R(6)
    x0 += ks0; x1 += ks1 + 3u;
    TF_R(17) TF_R(29) TF_R(16) TF_R(24)
    x0 += ks1; x1 += ks2 + 4u;
    TF_R(13) TF_R(15) TF_R(26) TF_R(6)
    x0 += ks2; x1 += ks0 + 5u;
#undef TF_R
    unsigned bits = x0 ^ x1;
    return __uint_as_float((bits >> 9) | 0x3f800000u) - 1.0f;
}

__device__ __forceinline__ bool keep_42(unsigned e) {
    float u = jax_uniform_42(e);
    return floorf(0.9f + u) != 0.0f;
}

// f32 -> bf16 round-to-nearest-even
__device__ __forceinline__ unsigned short f32_bf16(float f) {
    unsigned bits = __float_as_uint(f);
    return (unsigned short)((bits + 0x7fffu + ((bits >> 16) & 1u)) >> 16);
}

__device__ __forceinline__ float bf16_f32(unsigned short u) {
    return __uint_as_float((unsigned)u << 16);
}

// ---------------- phase 1 (R13 verbatim): LDS-binned grouping, 512 thr ---------
__global__ __launch_bounds__(512) void phase1(
        const float* __restrict__ fvals, const int* __restrict__ frows,
        const int* __restrict__ fcols,
        const float* __restrict__ avals, const int* __restrict__ arows,
        const int* __restrict__ acols,
        int* __restrict__ bcur_x, int* __restrict__ bcur_a,
        float2* __restrict__ gx, float2* __restrict__ ga) {
    const int isA = blockIdx.y;
    const float* vals = isA ? avals : fvals;
    const int* rows   = isA ? arows : frows;
    const int* cols   = isA ? acols : fcols;
    int* bcur         = isA ? bcur_a : bcur_x;
    float2* dst       = isA ? ga : gx;
    const unsigned cap = isA ? CAPA : CAPX;
    const unsigned n  = isA ? N_EDGES : NNZ_X;

    unsigned t = threadIdx.x;
    unsigned base = blockIdx.x * CHUNK;
    if (base >= n) return;

    __shared__ int cnt[512];
    __shared__ int start[512];
    __shared__ int cur[512];
    __shared__ int gbase[NB];
    __shared__ int s[256];
    __shared__ unsigned pArr[CHUNK];   // (b<<20)|(rowlow<<12)|ilocal

    int rcache[KPT];

    cnt[t] = 0;
    __syncthreads();
    #pragma unroll
    for (int k = 0; k < KPT; k++) {
        unsigned i = base + k * 512u + t;
        int r = -1;
        if (i < n) {
            int rr = rows[i];
            if (isA || keep_42(i)) r = rr;
        }
        rcache[k] = r;
        if (r >= 0) atomicAdd(&cnt[(unsigned)r >> 8], 1);
    }
    __syncthreads();
    if (t < 256) s[t] = cnt[2*t] + cnt[2*t+1];
    __syncthreads();
    for (int off = 1; off < 256; off <<= 1) {
        int v = (t < 256u && t >= (unsigned)off) ? s[t - off] : 0;
        __syncthreads();
        if (t < 256u) s[t] += v;
        __syncthreads();
    }
    if (t < 256u) {
        int excl = t ? s[t-1] : 0;
        start[2*t]   = excl;
        start[2*t+1] = excl + cnt[2*t];
        cur[2*t]     = excl;
        cur[2*t+1]   = excl + cnt[2*t];
    }
    for (unsigned b = t; b < NB; b += 512u) {
        int cb = cnt[b];
        if (cb > 0) gbase[b] = atomicAdd(&bcur[b], cb);
    }
    __syncthreads();
    int n_valid = s[255];
    #pragma unroll
    for (int k = 0; k < KPT; k++) {
        int r = rcache[k];
        if (r >= 0) {
            unsigned b = (unsigned)r >> 8;
            int p = atomicAdd(&cur[b], 1);
            pArr[p] = (b << 20) | (((unsigned)r & 255u) << 12) | (k * 512u + t);
        }
    }
    __syncthreads();
    #pragma unroll
    for (int k = 0; k < KPT; k++) {
        int sidx = k * 512 + (int)t;
        if (sidx < n_valid) {
            unsigned m = pArr[sidx];
            unsigned b = m >> 20;
            unsigned rowlow = (m >> 12) & 255u;
            unsigned i = base + (m & 4095u);
            float v = vals[i];
            if (!isA) v *= (float)(1.0 / 0.9);
            unsigned packed = ((unsigned)cols[i] << 8) | rowlow;
            float2 e; e.x = v; e.y = __int_as_float((int)packed);
            dst[(size_t)b * cap + gbase[b] + (sidx - start[b])] = e;
        }
    }
}

// ---------------- sort stage: grid 2*NB, LDS = CAPX only ----------------------
// blocks [0, NB):    X bucket -> LDS row-sort -> SpMM1 (quarter-wave W) -> bf16 xw
// blocks [NB, 2*NB): A bucket -> register-staged in-place sort + rs_a
__global__ __launch_bounds__(512) void sort_stage(
        const int* __restrict__ bcur_x, const float2* __restrict__ gx,
        const float* __restrict__ W, unsigned short* __restrict__ xw,
        const int* __restrict__ bcur_a, float2* __restrict__ ga,
        unsigned short* __restrict__ rs) {
    __shared__ float2 ent[CAPX];       // 34.8 KB
    __shared__ int hist[256];
    __shared__ int starts[256];
    __shared__ int cursor[256];
    __shared__ int wtot[4];
    unsigned t = threadIdx.x;
    unsigned wid = t >> 6, lane = t & 63u;
    const int isA = (blockIdx.x >= NB);
    unsigned b = isA ? (blockIdx.x - NB) : blockIdx.x;

    if (!isA) {
        // ================= X path =================
        int cnt = bcur_x[b];
        const float2* src = gx + (size_t)b * CAPX;
        if (t < 256) hist[t] = 0;
        __syncthreads();
        for (int i = (int)t; i < cnt; i += 512)
            atomicAdd(&hist[((unsigned)__float_as_int(src[i].y)) & 255u], 1);
        __syncthreads();
        int inc = 0, binv = 0;
        if (wid < 4u) {
            unsigned bin = wid * 64u + lane;
            binv = hist[bin];
            inc = binv;
            #pragma unroll
            for (int d = 1; d < 64; d <<= 1) {
                int v = __shfl_up(inc, d, 64);
                if (lane >= (unsigned)d) inc += v;
            }
            if (lane == 63u) wtot[wid] = inc;
        }
        __syncthreads();
        if (wid < 4u) {
            int offw = 0;
            #pragma unroll
            for (int w = 0; w < 4; w++) if ((unsigned)w < wid) offw += wtot[w];
            unsigned bin = wid * 64u + lane;
            int excl = inc - binv + offw;
            starts[bin] = excl;
            cursor[bin] = excl;
        }
        __syncthreads();
        for (int i = (int)t; i < cnt; i += 512) {
            float2 e = src[i];
            int pos = atomicAdd(&cursor[((unsigned)__float_as_int(e.y)) & 255u], 1);
            ent[pos] = e;
        }
        __syncthreads();
        // SpMM1: 8 waves x 32 rows; quarter-wave float4 W gathers
        unsigned quarter = lane >> 4, sub = lane & 15u;
        const float4* W4 = (const float4*)W;       // row stride 16 float4
        ushort4* xw4 = (ushort4*)xw;               // row stride 16 ushort4
        for (unsigned r = wid; r < 256u; r += 8u) {
            int s0 = starts[r];
            int s1 = (r == 255u) ? cnt : starts[r + 1];
            float4 acc[4];
            #pragma unroll
            for (int j = 0; j < 4; j++) { acc[j].x = acc[j].y = acc[j].z = acc[j].w = 0.0f; }
            int p = s0;
            for (; p + 16 <= s1; p += 16) {
                float2 e[4];
                #pragma unroll
                for (int j = 0; j < 4; j++) e[j] = ent[p + 4 * quarter + j];
                float4 w[4];
                #pragma unroll
                for (int j = 0; j < 4; j++)
                    w[j] = W4[(((unsigned)__float_as_int(e[j].y)) >> 8) * 16u + sub];
                #pragma unroll
                for (int j = 0; j < 4; j++) {
                    acc[j].x = fmaf(e[j].x, w[j].x, acc[j].x);
                    acc[j].y = fmaf(e[j].x, w[j].y, acc[j].y);
                    acc[j].z = fmaf(e[j].x, w[j].z, acc[j].z);
                    acc[j].w = fmaf(e[j].x, w[j].w, acc[j].w);
                }
            }
            for (int q = p + (int)quarter; q < s1; q += 4) {
                float2 e = ent[q];
                float4 w = W4[(((unsigned)__float_as_int(e.y)) >> 8) * 16u + sub];
                acc[0].x = fmaf(e.x, w.x, acc[0].x);
                acc[0].y = fmaf(e.x, w.y, acc[0].y);
                acc[0].z = fmaf(e.x, w.z, acc[0].z);
                acc[0].w = fmaf(e.x, w.w, acc[0].w);
            }
            float ax = (acc[0].x + acc[1].x) + (acc[2].x + acc[3].x);
            float ay = (acc[0].y + acc[1].y) + (acc[2].y + acc[3].y);
            float az = (acc[0].z + acc[1].z) + (acc[2].z + acc[3].z);
            float aw = (acc[0].w + acc[1].w) + (acc[2].w + acc[3].w);
            ax += __shfl(ax, (int)(lane ^ 16u), 64);
            ay += __shfl(ay, (int)(lane ^ 16u), 64);
            az += __shfl(az, (int)(lane ^ 16u), 64);
            aw += __shfl(aw, (int)(lane ^ 16u), 64);
            ax += __shfl(ax, (int)(lane ^ 32u), 64);
            ay += __shfl(ay, (int)(lane ^ 32u), 64);
            az += __shfl(az, (int)(lane ^ 32u), 64);
            aw += __shfl(aw, (int)(lane ^ 32u), 64);
            unsigned grow = (b << 8) + r;
            if (quarter == 0 && grow < N_NODES) {
                ushort4 o;
                o.x = f32_bf16(ax); o.y = f32_bf16(ay);
                o.z = f32_bf16(az); o.w = f32_bf16(aw);
                xw4[(size_t)grow * 16u + sub] = o;
            }
        }
    } else {
        // ================= A path (R13 verbatim): register-staged sort =========
        int cnt = bcur_a[b];
        float2* g = ga + (size_t)b * CAPA;
        if (t < 256) hist[t] = 0;
        __syncthreads();
        float2 ec[10];
        #pragma unroll
        for (int k = 0; k < 10; k++) {
            int i = k * 512 + (int)t;
            if (i < cnt) {
                float2 e = g[i];
                ec[k] = e;
                atomicAdd(&hist[((unsigned)__float_as_int(e.y)) & 255u], 1);
            }
        }
        __syncthreads();
        int inc = 0, binv = 0;
        if (wid < 4u) {
            unsigned bin = wid * 64u + lane;
            binv = hist[bin];
            inc = binv;
            #pragma unroll
            for (int d = 1; d < 64; d <<= 1) {
                int v = __shfl_up(inc, d, 64);
                if (lane >= (unsigned)d) inc += v;
            }
            if (lane == 63u) wtot[wid] = inc;
        }
        __syncthreads();
        if (wid < 4u) {
            int offw = 0;
            #pragma unroll
            for (int w = 0; w < 4; w++) if ((unsigned)w < wid) offw += wtot[w];
            unsigned bin = wid * 64u + lane;
            int excl = inc - binv + offw;
            cursor[bin] = excl;
            rs[(b << 8) + bin] = (unsigned short)excl;
        }
        __syncthreads();
        #pragma unroll
        for (int k = 0; k < 10; k++) {
            int i = k * 512 + (int)t;
            if (i < cnt) {
                unsigned packed = (unsigned)__float_as_int(ec[k].y);
                int pos = atomicAdd(&cursor[packed & 255u], 1);
                float2 o; o.x = ec[k].x; o.y = __int_as_float((int)(packed >> 8));
                g[pos] = o;
            }
        }
    }
}

// ---------------- SpMM2 + ReLU: quarter-wave ushort4 gather --------------------
// lane = (quarter, dim-quad): 16 lanes cover a row via ushort4 (4 bf16 dims).
// Per 16-entry batch each quarter gathers 4 -> VMEM instr halved vs half-wave.
__global__ void spmm2(const int* __restrict__ bcur_a,
                      const unsigned short* __restrict__ rs_a,
                      const float2* __restrict__ ga,
                      const unsigned short* __restrict__ xw,
                      float* __restrict__ out) {
    unsigned row  = blockIdx.x * 4u + (threadIdx.x >> 6);
    unsigned lane = threadIdx.x & 63u;
    if (row >= N_NODES) return;
    unsigned b = row >> 8, rl = row & 255u;
    int cnt = bcur_a[b];
    const float2* ent = ga + (size_t)b * CAPA;
    int s0 = rs_a[row];
    int s1 = (rl == 255u) ? cnt : (int)rs_a[row + 1];
    unsigned quarter = lane >> 4;
    unsigned sub     = lane & 15u;
    const ushort4* xw4 = (const ushort4*)xw;   // row stride = 16 ushort4

    float4 acc[4];
    #pragma unroll
    for (int j = 0; j < 4; j++) { acc[j].x = acc[j].y = acc[j].z = acc[j].w = 0.0f; }
    int p = s0;
    for (; p + 16 <= s1; p += 16) {
        float2 e[4];
        #pragma unroll
        for (int j = 0; j < 4; j++) e[j] = ent[p + 4 * quarter + j];
        ushort4 u[4];
        #pragma unroll
        for (int j = 0; j < 4; j++)
            u[j] = xw4[((unsigned)__float_as_int(e[j].y)) * 16u + sub];
        #pragma unroll
        for (int j = 0; j < 4; j++) {
            acc[j].x = fmaf(e[j].x, bf16_f32(u[j].x), acc[j].x);
            acc[j].y = fmaf(e[j].x, bf16_f32(u[j].y), acc[j].y);
            acc[j].z = fmaf(e[j].x, bf16_f32(u[j].z), acc[j].z);
            acc[j].w = fmaf(e[j].x, bf16_f32(u[j].w), acc[j].w);
        }
    }
    for (int q = p + (int)quarter; q < s1; q += 4) {
        float2 e = ent[q];
        ushort4 u = xw4[((unsigned)__float_as_int(e.y)) * 16u + sub];
        acc[0].x = fmaf(e.x, bf16_f32(u.x), acc[0].x);
        acc[0].y = fmaf(e.x, bf16_f32(u.y), acc[0].y);
        acc[0].z = fmaf(e.x, bf16_f32(u.z), acc[0].z);
        acc[0].w = fmaf(e.x, bf16_f32(u.w), acc[0].w);
    }
    float ax = (acc[0].x + acc[1].x) + (acc[2].x + acc[3].x);
    float ay = (acc[0].y + acc[1].y) + (acc[2].y + acc[3].y);
    float az = (acc[0].z + acc[1].z) + (acc[2].z + acc[3].z);
    float aw = (acc[0].w + acc[1].w) + (acc[2].w + acc[3].w);
    ax += __shfl(ax, (int)(lane ^ 16u), 64);
    ay += __shfl(ay, (int)(lane ^ 16u), 64);
    az += __shfl(az, (int)(lane ^ 16u), 64);
    aw += __shfl(aw, (int)(lane ^ 16u), 64);
    ax += __shfl(ax, (int)(lane ^ 32u), 64);
    ay += __shfl(ay, (int)(lane ^ 32u), 64);
    az += __shfl(az, (int)(lane ^ 32u), 64);
    aw += __shfl(aw, (int)(lane ^ 32u), 64);
    if (quarter == 0) {
        float4 o;
        o.x = fmaxf(ax, 0.0f);
        o.y = fmaxf(ay, 0.0f);
        o.z = fmaxf(az, 0.0f);
        o.w = fmaxf(aw, 0.0f);
        ((float4*)out)[(size_t)row * 16u + sub] = o;
    }
}

extern "C" void kernel_launch(void* const* d_in, const int* in_sizes, int n_in,
                              void* d_out, int out_size, void* d_ws, size_t ws_size,
                              hipStream_t stream) {
    const float* feat_values = (const float*)d_in[0];
    const float* W           = (const float*)d_in[1];
    const float* adj_values  = (const float*)d_in[2];
    const int*   feat_rows   = (const int*)d_in[3];
    const int*   feat_cols   = (const int*)d_in[4];
    const int*   adj_rows    = (const int*)d_in[5];
    const int*   adj_cols    = (const int*)d_in[6];
    float* out = (float*)d_out;

    // ---- workspace layout (bytes) ----
    char* ws = (char*)d_ws;
    int* bcur_x = (int*)(ws + 0);
    int* bcur_a = (int*)(ws + 2048);
    unsigned short* rs_a = (unsigned short*)(ws + 4096);
    float2* gx  = (float2*)(ws + 204800);
    float2* ga  = (float2*)(ws + 13817856);
    unsigned short* xw = (unsigned short*)(ws + 29833216);

    hipMemsetAsync(ws, 0, 4096, stream);    // bucket cursors

    dim3 gp1((N_EDGES + CHUNK - 1) / CHUNK, 2);
    phase1<<<gp1, 512, 0, stream>>>(feat_values, feat_rows, feat_cols,
                                    adj_values, adj_rows, adj_cols,
                                    bcur_x, bcur_a, gx, ga);
    sort_stage<<<2 * NB, 512, 0, stream>>>(bcur_x, gx, W, xw, bcur_a, ga, rs_a);
    spmm2<<<(N_NODES + 3) / 4, 256, 0, stream>>>(bcur_a, rs_a, ga, xw, out);
}